// Round 6
// baseline (906.302 us; speedup 1.0000x reference)
//
#include <hip/hip_runtime.h>
#include <hip/hip_bf16.h>
#include <math.h>

// Problem constants
#define TT   128
#define BB   256
#define DIN  256
#define DH   1024
#define DOUT 256

// Lineage: R3 shape -> R9 flagless epoch-in-LSB sync -> R11 fragment-order H
// exchange -> R13 (best micro-structure, 605us steady): paced scattered probe
// (lane l watches frag (l&31), s_sleep(2)) gating a 2-deep chained chunk
// pipeline. R12/R14/R15/R16 post-mortems: EVERY change that added traffic or
// burst width to the sync window regressed (retry storm / probe congestion /
// early flags / 64-wide burst + compiler vmcnt(0) conservatism in WAITVALID's
// retry loop). Micro-structure is exhausted.
//
// R17: STRUCTURAL -- halve the exchange. Read volume/step = NGN x 512KB, all
// via LLC (agent-scope bypasses non-coherent L2). NC 32->64 (W1h slice =
// 128KB dynamic LDS, gfx950-proven workgroup size), NGN 32->16, 128 blocks:
//   - exchange 16->8 MB/step, xs dup 8->4 MB/step, spinners 512->256
//   - straggler pool per row-tile 32->16 producers
//   - per-wave compute doubles (160 MFMA/step) -> wider window hiding
//     producer finish under x-phase
// h-phase gate/chain is byte-exact R13; CONS now does 4 MFMAs/ks (ct=0..3).
// Hbuf fragment layout UNCHANGED (ks absolute = col/32; producer gn writes
// frags 2gn,2gn+1) -> readout kernel untouched. 1 block/CU, 2 waves/block ->
// <=1 wave/SIMD -> ~512 VGPR headroom for wx[4][8]+xf+chunk buffers.
#define NGM 8
#define MR  32
#define NGN 16
#define NC  64

typedef float  floatx4 __attribute__((ext_vector_type(4)));
typedef short  shortx8 __attribute__((ext_vector_type(8)));
typedef unsigned long long u64;

#define CMASK 0x0001000100010001ULL
#define GSTRIDE 32768           // shorts per group slab (2*32*4*16*8)

// dynamic-LDS W1h A-fragment index (shorts): [ks 0..31][ct 0..3][qq 0..3][c 0..15][j 0..7]
#define WHL(ks, ct, qq, c) ((((ks) * 16 + (ct) * 4 + (qq)) * 128) + (c) * 8)

__device__ __forceinline__ short f2bf(float f) {
    union { float f; unsigned u; } v; v.f = f;
    unsigned r = v.u + 0x7fffu + ((v.u >> 16) & 1u);   // RNE, inputs never NaN
    return (short)(r >> 16);
}

// RNE to the bf16 grid restricted to LSB==bit (step 2 ulp): err <= 1 ulp bf16
__device__ __forceinline__ unsigned short bf15e(float v, unsigned bit) {
    union { float f; unsigned u; } x; x.f = v;
    unsigned ua = x.u - (bit << 16);
    unsigned k  = (ua + 0xFFFFu + ((ua >> 17) & 1u)) >> 17;
    return (unsigned short)((k << 1) | bit);
}

__device__ __forceinline__ shortx8 mk8(u64 lo, u64 hi) {
    union { struct { u64 a, b; } s; shortx8 v; } u;
    u.s.a = lo; u.s.b = hi;
    return u.v;
}

__device__ __forceinline__ float fast_tanh(float z) {
    float e = __expf(2.0f * fabsf(z));
    float r = 1.0f - 2.0f / (e + 1.0f);
    return copysignf(r, z);
}

#define AGLD(p)    __hip_atomic_load((p),  __ATOMIC_RELAXED, __HIP_MEMORY_SCOPE_AGENT)
#define AGST(p, v) __hip_atomic_store((p), (v), __ATOMIC_RELAXED, __HIP_MEMORY_SCOPE_AGENT)

// hfr = group slab base + rt*16384 + q*128 + lr*8 ; frag ks at +ks*512.
// One chunk = 8 ks fragments = 16 u64 AGLDs, COALESCED across lanes.
#define LD16(buf, base) do { \
    _Pragma("unroll") \
    for (int _j = 0; _j < 8; ++_j) { \
        const u64* _p = (const u64*)(hfr + ((base) + _j) * 512); \
        buf[2 * _j]     = AGLD(_p); \
        buf[2 * _j + 1] = AGLD(_p + 1); \
    } } while (0)
#define OK16(buf, okvar) do { \
    int _o = 1; \
    _Pragma("unroll") \
    for (int _j = 0; _j < 16; ++_j) _o &= ((buf[_j] & CMASK) == pat); \
    okvar = __all(_o); } while (0)
#define WAITVALID(buf, base) do { \
    int _okk; OK16(buf, _okk); \
    while (!_okk) { __builtin_amdgcn_s_sleep(1); LD16(buf, base); OK16(buf, _okk); } \
    } while (0)
// consume one chunk: per ks fragment, 4 MFMAs (ct = 0..3) into acc[0..3]
#define CONS16(buf, base, acc) do { \
    _Pragma("unroll") \
    for (int _j = 0; _j < 8; ++_j) { \
        shortx8 bfr = mk8(buf[2 * _j], buf[2 * _j + 1]); \
        shortx8 a0 = *(const shortx8*)&WhL[WHL((base) + _j, 0, q, lr)]; \
        shortx8 a1 = *(const shortx8*)&WhL[WHL((base) + _j, 1, q, lr)]; \
        shortx8 a2 = *(const shortx8*)&WhL[WHL((base) + _j, 2, q, lr)]; \
        shortx8 a3 = *(const shortx8*)&WhL[WHL((base) + _j, 3, q, lr)]; \
        acc[0] = __builtin_amdgcn_mfma_f32_16x16x32_bf16(a0, bfr, acc[0], 0, 0, 0); \
        acc[1] = __builtin_amdgcn_mfma_f32_16x16x32_bf16(a1, bfr, acc[1], 0, 0, 0); \
        acc[2] = __builtin_amdgcn_mfma_f32_16x16x32_bf16(a2, bfr, acc[2], 0, 0, 0); \
        acc[3] = __builtin_amdgcn_mfma_f32_16x16x32_bf16(a3, bfr, acc[3], 0, 0, 0); \
    } } while (0)

__global__ __launch_bounds__(128, 1) void rnn_steps_kernel(
    const float* __restrict__ xs, const float* __restrict__ W1x,
    const float* __restrict__ W1h, const float* __restrict__ b1,
    short* __restrict__ Hbuf)
{
    const int gm  = blockIdx.x;   // 0..7 row group
    const int gn  = blockIdx.y;   // 0..15 col block (64 cols)
    const int tid = threadIdx.x;
    const int w   = tid >> 6;     // wave -> 16-row tile
    const int l   = tid & 63;
    const int lr  = l & 15;
    const int q   = l >> 4;       // MFMA k-quad

    const int r0 = gm * MR;
    const int c0 = gn * NC;

    // W1h slice as MFMA A-fragments, 128 KB dynamic LDS
    extern __shared__ __align__(16) short WhL[];
    for (int idx = tid; idx < (DH / 32) * 4 * 4 * 16; idx += 128) {
        const int c  = idx & 15;
        const int qq = (idx >> 4) & 3;
        const int ct = (idx >> 6) & 3;
        const int ks = idx >> 8;
        shortx8 f;
        #pragma unroll
        for (int j = 0; j < 8; ++j)
            f[j] = f2bf(W1h[(size_t)(ks * 32 + qq * 8 + j) * DH + c0 + ct * 16 + c]);
        *(shortx8*)&WhL[WHL(ks, ct, qq, c)] = f;
    }
    // W1x A-fragments register-resident (128 VGPRs; <=1 wave/SIMD so fine)
    shortx8 wx[4][8];
    #pragma unroll
    for (int ct = 0; ct < 4; ++ct)
        #pragma unroll
        for (int ks = 0; ks < 8; ++ks) {
            shortx8 f;
            #pragma unroll
            for (int j = 0; j < 8; ++j)
                f[j] = f2bf(W1x[(size_t)(ks * 32 + q * 8 + j) * DH + c0 + ct * 16 + lr]);
            wx[ct][ks] = f;
        }
    __syncthreads();   // WhL ready; no barriers after this point

    floatx4 bias[4];
    #pragma unroll
    for (int ct = 0; ct < 4; ++ct)
        #pragma unroll
        for (int r = 0; r < 4; ++r) bias[ct][r] = b1[c0 + ct * 16 + q * 4 + r];

    const int myrow = r0 + w * 16 + lr;        // xs rows (unchanged)
    const size_t HS = (size_t)BB * DH;         // shorts per version

    // fragment-layout bases (consumer reads its own row-tile w)
    short* const Hg   = Hbuf + gm * GSTRIDE;
    const int rdoff   = w * 16384 + q * 128 + lr * 8;
    // producer store base: frag = gn*2 + (ct>>1), +256 shorts when (ct&1)
    const int wrbase  = w * 16384 + (q >> 1) * 128 + lr * 8 + (q & 1) * 4;
    // probe offset: lane l watches fragment (l&31) of its wave's row tile
    const int proff   = w * 16384 + (l & 31) * 512;

    // ---- xs register pipeline: xf holds x_t, loaded during step t-1 ----
    floatx4 xf[16];
    {
        const float* xrow = xs + (size_t)myrow * DIN + q * 8;   // t = 1
        #pragma unroll
        for (int ks = 0; ks < 8; ++ks) {
            xf[2 * ks]     = *(const floatx4*)(xrow + ks * 32);
            xf[2 * ks + 1] = *(const floatx4*)(xrow + ks * 32 + 4);
        }
    }

    for (int t = 1; t <= TT; ++t) {
        const short* const hfr = Hg + (size_t)((t - 1) & 1) * HS + rdoff;
        // expected epoch code for h_{t-1}: 1+((t-2)%15) in [1,15]; t=1 unused.
        const int pc = (t >= 2) ? (1 + ((t - 2) % 15)) : 0;
        const u64 pat = ((u64)(pc & 1)) | ((u64)((pc >> 1) & 1) << 16) |
                        ((u64)((pc >> 2) & 1) << 32) | ((u64)((pc >> 3) & 1) << 48);

        // ---- issue the one-load readiness probe; result checked after x ----
        const u64* const pp = (const u64*)(Hg + (size_t)((t - 1) & 1) * HS + proff);
        u64 pv = 0;
        if (t > 1) pv = AGLD(pp);

        floatx4 accA[4], accB[4];
        #pragma unroll
        for (int ct = 0; ct < 4; ++ct) {
            accA[ct] = (floatx4){0.f, 0.f, 0.f, 0.f};
            accB[ct] = (floatx4){0.f, 0.f, 0.f, 0.f};
        }

        // ---- x_t @ W1x from the register pipeline (no memory on this path) ----
        #pragma unroll
        for (int ks = 0; ks < 8; ++ks) {
            floatx4 x0 = xf[2 * ks], x1 = xf[2 * ks + 1];
            shortx8 b;
            b[0] = f2bf(x0[0]); b[1] = f2bf(x0[1]); b[2] = f2bf(x0[2]); b[3] = f2bf(x0[3]);
            b[4] = f2bf(x1[0]); b[5] = f2bf(x1[1]); b[6] = f2bf(x1[2]); b[7] = f2bf(x1[3]);
            accA[0] = __builtin_amdgcn_mfma_f32_16x16x32_bf16(wx[0][ks], b, accA[0], 0, 0, 0);
            accA[1] = __builtin_amdgcn_mfma_f32_16x16x32_bf16(wx[1][ks], b, accA[1], 0, 0, 0);
            accA[2] = __builtin_amdgcn_mfma_f32_16x16x32_bf16(wx[2][ks], b, accA[2], 0, 0, 0);
            accA[3] = __builtin_amdgcn_mfma_f32_16x16x32_bf16(wx[3][ks], b, accA[3], 0, 0, 0);
        }

        // ---- fire xs loads for step t+1 BEFORE the spin: their HBM drain
        //      overlaps detection (in-order vmcnt retirement) ----
        if (t < TT) {
            const float* xrow = xs + ((size_t)t * BB + myrow) * DIN + q * 8;
            #pragma unroll
            for (int ks = 0; ks < 8; ++ks) {
                xf[2 * ks]     = *(const floatx4*)(xrow + ks * 32);
                xf[2 * ks + 1] = *(const floatx4*)(xrow + ks * 32 + 4);
            }
        }

        // ---- h_{t-1} @ W1h: R13-proven paced gate + 2-deep chained chunks ----
        if (t > 1) {
            // paced probe spin: one 8B load per cycle watches all 32 fragments
            while (!__all((pv & CMASK) == pat)) {
                __builtin_amdgcn_s_sleep(2);
                pv = AGLD(pp);
            }
            u64 A[16], B[16];
            LD16(A, 0);  LD16(B, 8);
            WAITVALID(A, 0);  CONS16(A, 0,  accA);
            LD16(A, 16);
            WAITVALID(B, 8);  CONS16(B, 8,  accB);
            LD16(B, 24);
            WAITVALID(A, 16); CONS16(A, 16, accA);
            WAITVALID(B, 24); CONS16(B, 24, accB);
        }

        // ---- tanh, encode epoch bits, four 8B coalesced AGSTs ----
        {
            const int cc = 1 + ((t - 1) % 15);     // code(t), never 0 (=poison)
            short* const hp_base = Hg + (size_t)(t & 1) * HS + wrbase;
            #pragma unroll
            for (int ct = 0; ct < 4; ++ct) {
                const floatx4 acc = accA[ct] + accB[ct];
                u64 p = 0;
                #pragma unroll
                for (int r = 0; r < 4; ++r) {
                    const unsigned bit = ((unsigned)cc >> r) & 1u;
                    p |= ((u64)bf15e(fast_tanh(acc[r] + bias[ct][r]), bit)) << (16 * r);
                }
                AGST((u64*)(hp_base + (gn * 2 + (ct >> 1)) * 512 + (ct & 1) * 256), p);
            }
            // fire-and-forget: words self-validate at consumers
        }
    }
}

// out[b][o] = sum_k h[b][k]*W2[k][o] + b2. Final h (t=128 -> parity 0) is in
// fragment layout; decode while staging via AGLD into LDS in natural order.
__global__ __launch_bounds__(256) void readout_kernel(
    const short* __restrict__ Hfin, const float* __restrict__ W2,
    const float* __restrict__ b2, float* __restrict__ out)
{
    const int o  = threadIdx.x;
    const int b0 = blockIdx.x * 4;
    __shared__ u64 hs8[4 * DH / 4];            // [row][col/4], 8 KB
    for (int ch = o; ch < 4 * DH / 4; ch += 256) {
        const int row  = ch >> 8;              // 0..3
        const int col0 = (ch & 255) * 4;       // 0,4,..,1020
        const int rr   = b0 + row;
        const int gmr  = rr >> 5, rt = (rr >> 4) & 1, lrr = rr & 15;
        const int ks   = col0 >> 5, qq = (col0 >> 3) & 3, j0 = col0 & 7;
        const u64* src = (const u64*)(Hfin + (size_t)gmr * GSTRIDE + rt * 16384 +
                                      ks * 512 + qq * 128 + lrr * 8 + j0);
        hs8[ch] = AGLD(src);
    }
    __syncthreads();
    const unsigned* h0 = (const unsigned*)&hs8[0 * 256];
    const unsigned* h1 = (const unsigned*)&hs8[1 * 256];
    const unsigned* h2 = (const unsigned*)&hs8[2 * 256];
    const unsigned* h3 = (const unsigned*)&hs8[3 * 256];
    float a0 = 0.f, a1 = 0.f, a2 = 0.f, a3 = 0.f;
    for (int k2 = 0; k2 < DH / 2; ++k2) {
        float w0 = W2[(2 * k2)     * DOUT + o];
        float w1 = W2[(2 * k2 + 1) * DOUT + o];
        unsigned p0 = h0[k2], p1 = h1[k2], p2 = h2[k2], p3 = h3[k2];
        a0 += __builtin_bit_cast(float, p0 << 16) * w0 + __builtin_bit_cast(float, p0 & 0xffff0000u) * w1;
        a1 += __builtin_bit_cast(float, p1 << 16) * w0 + __builtin_bit_cast(float, p1 & 0xffff0000u) * w1;
        a2 += __builtin_bit_cast(float, p2 << 16) * w0 + __builtin_bit_cast(float, p2 & 0xffff0000u) * w1;
        a3 += __builtin_bit_cast(float, p3 << 16) * w0 + __builtin_bit_cast(float, p3 & 0xffff0000u) * w1;
    }
    const float bias = b2[0];
    out[(b0 + 0) * DOUT + o] = a0 + bias;
    out[(b0 + 1) * DOUT + o] = a1 + bias;
    out[(b0 + 2) * DOUT + o] = a2 + bias;
    out[(b0 + 3) * DOUT + o] = a3 + bias;
}

extern "C" void kernel_launch(void* const* d_in, const int* in_sizes, int n_in,
                              void* d_out, int out_size, void* d_ws, size_t ws_size,
                              hipStream_t stream) {
    (void)in_sizes; (void)n_in; (void)out_size; (void)ws_size;
    const float* xs  = (const float*)d_in[0];   // [128,256,256]
    const float* W1x = (const float*)d_in[1];   // [256,1024]
    const float* W1h = (const float*)d_in[2];   // [1024,1024]
    const float* b1  = (const float*)d_in[3];   // [1024]
    const float* W2  = (const float*)d_in[4];   // [1024,256]
    const float* b2  = (const float*)d_in[5];   // scalar
    float* out = (float*)d_out;                 // [256,256]

    // ws: H parity double buffer (1 MB), fragment layout. No flags, no memset:
    // 0xAA poison -> code 0, never matches any expected code (1..15) -> retry.
    short* Hbuf = (short*)d_ws;

    // 128 KB dynamic LDS opt-in (host-side attribute set; not a stream op, so
    // graph-capture safe). Set once per process.
    static bool lds_attr_done = false;
    if (!lds_attr_done) {
        hipFuncSetAttribute(reinterpret_cast<const void*>(rnn_steps_kernel),
                            hipFuncAttributeMaxDynamicSharedMemorySize, 131072);
        lds_attr_done = true;
    }

    rnn_steps_kernel<<<dim3(NGM, NGN), 128, 131072, stream>>>(xs, W1x, W1h, b1, Hbuf);
    // t=128 -> parity 0 holds h_128
    readout_kernel<<<dim3(BB / 4), 256, 0, stream>>>(Hbuf, W2, b2, out);
}

// Round 7
// 671.503 us; speedup vs baseline: 1.3497x; 1.3497x over previous
//
#include <hip/hip_runtime.h>
#include <hip/hip_bf16.h>
#include <math.h>

// Problem constants
#define TT   128
#define BB   256
#define DIN  256
#define DH   1024
#define DOUT 256

// R3-proven shape: 8 row-groups (32 rows) x 32 col-blocks (32 cols), 128 thr,
// 256 blocks, 64KB LDS. R9 flagless sync (epoch bit stolen from each bf16 LSB;
// every 8B word self-validates; AGLD/AGST agent-scope only; no fences, no
// flags, no barriers in the loop). R11: H in MFMA B-fragment order so the
// exchange is fully coalesced. R13 (best, 605us steady / 674 reported): paced
// scattered probe (lane l watches fragment (l&31)'s first word) gating a
// 2-deep chained chunk pipeline; WAITVALID retry rare.
//
// SESSION LEDGER (why this file is byte-R13 + one knob): every perturbation
// of the sync neighborhood regressed --
//   R12 deep-prefetch + any-order retry: retry storm, +35%
//   R14 dual-half sleepless probe + full burst: probe congestion, +16%
//   R15 producer-side flags: flags pass before data drains, +45% + 21ms outlier
//   R16 full-tile 64-load burst alone: compiler vmcnt conservatism in
//       WAITVALID's retry loop drains everything, +11%
//   R17 NC=64 structural: serial chain lengthened (4x tail), +37% + 41ms outlier
// Design law: gate must probe the data itself, paced, retries rare; burst
// must stay 2-deep chained; 32-producer shape is right.
//
// R18: exact R13 + ONE knob: gate spin s_sleep(2) -> s_sleep(1). Halves the
// detection quantization (~64 cyc) at identical per-poll probe footprint
// (same single load, same 32 lines); poll rate rises only modestly because
// the dependent-load RTT dominates the spin iteration.
#define NGM 8
#define MR  32
#define NGN 32
#define NC  32

typedef float  floatx4 __attribute__((ext_vector_type(4)));
typedef short  shortx8 __attribute__((ext_vector_type(8)));
typedef unsigned long long u64;

#define CMASK 0x0001000100010001ULL
#define GSTRIDE 32768           // shorts per group slab (2*32*4*16*8)

__device__ __forceinline__ short f2bf(float f) {
    union { float f; unsigned u; } v; v.f = f;
    unsigned r = v.u + 0x7fffu + ((v.u >> 16) & 1u);   // RNE, inputs never NaN
    return (short)(r >> 16);
}

// RNE to the bf16 grid restricted to LSB==bit (step 2 ulp): err <= 1 ulp bf16
__device__ __forceinline__ unsigned short bf15e(float v, unsigned bit) {
    union { float f; unsigned u; } x; x.f = v;
    unsigned ua = x.u - (bit << 16);
    unsigned k  = (ua + 0xFFFFu + ((ua >> 17) & 1u)) >> 17;
    return (unsigned short)((k << 1) | bit);
}

__device__ __forceinline__ shortx8 mk8(u64 lo, u64 hi) {
    union { struct { u64 a, b; } s; shortx8 v; } u;
    u.s.a = lo; u.s.b = hi;
    return u.v;
}

__device__ __forceinline__ float fast_tanh(float z) {
    float e = __expf(2.0f * fabsf(z));
    float r = 1.0f - 2.0f / (e + 1.0f);
    return copysignf(r, z);
}

#define AGLD(p)    __hip_atomic_load((p),  __ATOMIC_RELAXED, __HIP_MEMORY_SCOPE_AGENT)
#define AGST(p, v) __hip_atomic_store((p), (v), __ATOMIC_RELAXED, __HIP_MEMORY_SCOPE_AGENT)

// hfr = group slab base + rt*16384 + q*128 + lr*8 ; frag ks at +ks*512.
// One chunk = 8 ks fragments = 16 u64 AGLDs, COALESCED across lanes.
#define LD16(buf, base) do { \
    _Pragma("unroll") \
    for (int _j = 0; _j < 8; ++_j) { \
        const u64* _p = (const u64*)(hfr + ((base) + _j) * 512); \
        buf[2 * _j]     = AGLD(_p); \
        buf[2 * _j + 1] = AGLD(_p + 1); \
    } } while (0)
#define OK16(buf, okvar) do { \
    int _o = 1; \
    _Pragma("unroll") \
    for (int _j = 0; _j < 16; ++_j) _o &= ((buf[_j] & CMASK) == pat); \
    okvar = __all(_o); } while (0)
#define WAITVALID(buf, base) do { \
    int _okk; OK16(buf, _okk); \
    while (!_okk) { __builtin_amdgcn_s_sleep(1); LD16(buf, base); OK16(buf, _okk); } \
    } while (0)
#define CONS16(buf, base, accX, accY) do { \
    _Pragma("unroll") \
    for (int _j = 0; _j < 8; ++_j) { \
        shortx8 bfr = mk8(buf[2 * _j], buf[2 * _j + 1]); \
        shortx8 a0 = *(const shortx8*)&WhL[(base) + _j][0][q][lr][0]; \
        shortx8 a1 = *(const shortx8*)&WhL[(base) + _j][1][q][lr][0]; \
        accX = __builtin_amdgcn_mfma_f32_16x16x32_bf16(a0, bfr, accX, 0, 0, 0); \
        accY = __builtin_amdgcn_mfma_f32_16x16x32_bf16(a1, bfr, accY, 0, 0, 0); \
    } } while (0)

__global__ __launch_bounds__(128, 1) void rnn_steps_kernel(
    const float* __restrict__ xs, const float* __restrict__ W1x,
    const float* __restrict__ W1h, const float* __restrict__ b1,
    short* __restrict__ Hbuf)
{
    const int gm  = blockIdx.x;   // 0..7 row group
    const int gn  = blockIdx.y;   // 0..31 col block
    const int tid = threadIdx.x;
    const int w   = tid >> 6;     // wave -> 16-row tile
    const int l   = tid & 63;
    const int lr  = l & 15;
    const int q   = l >> 4;       // MFMA k-quad

    const int r0 = gm * MR;
    const int c0 = gn * NC;

    // W1h slice as MFMA A-fragments in LDS (R3-proven layout)
    __shared__ short WhL[DH / 32][2][4][16][8];   // 64 KB
    for (int idx = tid; idx < (DH / 32) * 2 * 4 * 16; idx += 128) {
        const int c  = idx & 15;
        const int qq = (idx >> 4) & 3;
        const int ct = (idx >> 6) & 1;
        const int ks = idx >> 7;
        shortx8 f;
        #pragma unroll
        for (int j = 0; j < 8; ++j)
            f[j] = f2bf(W1h[(size_t)(ks * 32 + qq * 8 + j) * DH + c0 + ct * 16 + c]);
        *(shortx8*)&WhL[ks][ct][qq][c][0] = f;
    }
    // W1x A-fragments register-resident (32 VGPRs)
    shortx8 wx[2][8];
    #pragma unroll
    for (int ct = 0; ct < 2; ++ct)
        #pragma unroll
        for (int ks = 0; ks < 8; ++ks) {
            shortx8 f;
            #pragma unroll
            for (int j = 0; j < 8; ++j)
                f[j] = f2bf(W1x[(size_t)(ks * 32 + q * 8 + j) * DH + c0 + ct * 16 + lr]);
            wx[ct][ks] = f;
        }
    __syncthreads();   // WhL ready; no barriers after this point

    floatx4 bias[2];
    #pragma unroll
    for (int ct = 0; ct < 2; ++ct)
        #pragma unroll
        for (int r = 0; r < 4; ++r) bias[ct][r] = b1[c0 + ct * 16 + q * 4 + r];

    const int myrow = r0 + w * 16 + lr;        // xs rows (unchanged)
    const size_t HS = (size_t)BB * DH;         // shorts per version

    // fragment-layout bases (consumer reads its own row-tile w)
    short* const Hg   = Hbuf + gm * GSTRIDE;
    const int rdoff   = w * 16384 + q * 128 + lr * 8;
    // producer store offsets (ks=gn): [w][gn][ct*2+(q>>1)][lr][(q&1)*4]
    const int wroff   = w * 16384 + gn * 512 + (q >> 1) * 128 + lr * 8 + (q & 1) * 4;
    // probe offset: lane l watches fragment (l&31) of its wave's row tile
    const int proff   = w * 16384 + (l & 31) * 512;

    // ---- xs register pipeline: xf holds x_t, loaded during step t-1 ----
    floatx4 xf[16];
    {
        const float* xrow = xs + (size_t)myrow * DIN + q * 8;   // t = 1
        #pragma unroll
        for (int ks = 0; ks < 8; ++ks) {
            xf[2 * ks]     = *(const floatx4*)(xrow + ks * 32);
            xf[2 * ks + 1] = *(const floatx4*)(xrow + ks * 32 + 4);
        }
    }

    for (int t = 1; t <= TT; ++t) {
        const short* const hfr = Hg + (size_t)((t - 1) & 1) * HS + rdoff;
        // expected epoch code for h_{t-1}: 1+((t-2)%15) in [1,15]; t=1 unused.
        const int pc = (t >= 2) ? (1 + ((t - 2) % 15)) : 0;
        const u64 pat = ((u64)(pc & 1)) | ((u64)((pc >> 1) & 1) << 16) |
                        ((u64)((pc >> 2) & 1) << 32) | ((u64)((pc >> 3) & 1) << 48);

        // ---- issue the one-load readiness probe; result checked after x ----
        const u64* const pp = (const u64*)(Hg + (size_t)((t - 1) & 1) * HS + proff);
        u64 pv = 0;
        if (t > 1) pv = AGLD(pp);

        floatx4 accA0 = {0.f, 0.f, 0.f, 0.f}, accA1 = {0.f, 0.f, 0.f, 0.f};
        floatx4 accB0 = {0.f, 0.f, 0.f, 0.f}, accB1 = {0.f, 0.f, 0.f, 0.f};

        // ---- x_t @ W1x from the register pipeline (no memory on this path) ----
        #pragma unroll
        for (int ks = 0; ks < 8; ++ks) {
            floatx4 x0 = xf[2 * ks], x1 = xf[2 * ks + 1];
            shortx8 b;
            b[0] = f2bf(x0[0]); b[1] = f2bf(x0[1]); b[2] = f2bf(x0[2]); b[3] = f2bf(x0[3]);
            b[4] = f2bf(x1[0]); b[5] = f2bf(x1[1]); b[6] = f2bf(x1[2]); b[7] = f2bf(x1[3]);
            accA0 = __builtin_amdgcn_mfma_f32_16x16x32_bf16(wx[0][ks], b, accA0, 0, 0, 0);
            accA1 = __builtin_amdgcn_mfma_f32_16x16x32_bf16(wx[1][ks], b, accA1, 0, 0, 0);
        }

        // ---- fire xs loads for step t+1 BEFORE the spin: their HBM drain
        //      overlaps detection (in-order vmcnt retirement) ----
        if (t < TT) {
            const float* xrow = xs + ((size_t)t * BB + myrow) * DIN + q * 8;
            #pragma unroll
            for (int ks = 0; ks < 8; ++ks) {
                xf[2 * ks]     = *(const floatx4*)(xrow + ks * 32);
                xf[2 * ks + 1] = *(const floatx4*)(xrow + ks * 32 + 4);
            }
        }

        // ---- h_{t-1} @ W1h ----
        if (t > 1) {
            // paced probe spin: one 8B load per cycle watches all 32
            // fragments; s_sleep(1) (R18: halved detection quantization)
            while (!__all((pv & CMASK) == pat)) {
                __builtin_amdgcn_s_sleep(1);
                pv = AGLD(pp);
            }
            // tile is ready: chained 2-deep burst load / validate / consume.
            // OK16 retry survives the rare p0/p1 same-thread store-order race.
            u64 A[16], B[16];
            LD16(A, 0);  LD16(B, 8);
            WAITVALID(A, 0);  CONS16(A, 0,  accA0, accA1);
            LD16(A, 16);
            WAITVALID(B, 8);  CONS16(B, 8,  accB0, accB1);
            LD16(B, 24);
            WAITVALID(A, 16); CONS16(A, 16, accA0, accA1);
            WAITVALID(B, 24); CONS16(B, 24, accB0, accB1);
        }

        // ---- tanh, encode epoch bits, two 8B coalesced AGSTs ----
        {
            const floatx4 acc0 = accA0 + accB0;
            const floatx4 acc1 = accA1 + accB1;
            const int cc = 1 + ((t - 1) % 15);     // code(t), never 0 (=poison)
            short* hp = Hg + (size_t)(t & 1) * HS + wroff;
            u64 p0 = 0, p1 = 0;
            #pragma unroll
            for (int r = 0; r < 4; ++r) {
                const unsigned bit = ((unsigned)cc >> r) & 1u;
                p0 |= ((u64)bf15e(fast_tanh(acc0[r] + bias[0][r]), bit)) << (16 * r);
                p1 |= ((u64)bf15e(fast_tanh(acc1[r] + bias[1][r]), bit)) << (16 * r);
            }
            AGST((u64*)(hp), p0);            // ct=0
            AGST((u64*)(hp + 256), p1);      // ct=1 (+2*128 shorts)
            // fire-and-forget: words self-validate at consumers
        }
    }
}

// out[b][o] = sum_k h[b][k]*W2[k][o] + b2. Final h (t=128 -> parity 0) is in
// fragment layout; decode while staging via AGLD into LDS in natural order.
__global__ __launch_bounds__(256) void readout_kernel(
    const short* __restrict__ Hfin, const float* __restrict__ W2,
    const float* __restrict__ b2, float* __restrict__ out)
{
    const int o  = threadIdx.x;
    const int b0 = blockIdx.x * 4;
    __shared__ u64 hs8[4 * DH / 4];            // [row][col/4], 8 KB
    for (int ch = o; ch < 4 * DH / 4; ch += 256) {
        const int row  = ch >> 8;              // 0..3
        const int col0 = (ch & 255) * 4;       // 0,4,..,1020
        const int rr   = b0 + row;
        const int gmr  = rr >> 5, rt = (rr >> 4) & 1, lrr = rr & 15;
        const int ks   = col0 >> 5, qq = (col0 >> 3) & 3, j0 = col0 & 7;
        const u64* src = (const u64*)(Hfin + (size_t)gmr * GSTRIDE + rt * 16384 +
                                      ks * 512 + qq * 128 + lrr * 8 + j0);
        hs8[ch] = AGLD(src);
    }
    __syncthreads();
    const unsigned* h0 = (const unsigned*)&hs8[0 * 256];
    const unsigned* h1 = (const unsigned*)&hs8[1 * 256];
    const unsigned* h2 = (const unsigned*)&hs8[2 * 256];
    const unsigned* h3 = (const unsigned*)&hs8[3 * 256];
    float a0 = 0.f, a1 = 0.f, a2 = 0.f, a3 = 0.f;
    for (int k2 = 0; k2 < DH / 2; ++k2) {
        float w0 = W2[(2 * k2)     * DOUT + o];
        float w1 = W2[(2 * k2 + 1) * DOUT + o];
        unsigned p0 = h0[k2], p1 = h1[k2], p2 = h2[k2], p3 = h3[k2];
        a0 += __builtin_bit_cast(float, p0 << 16) * w0 + __builtin_bit_cast(float, p0 & 0xffff0000u) * w1;
        a1 += __builtin_bit_cast(float, p1 << 16) * w0 + __builtin_bit_cast(float, p1 & 0xffff0000u) * w1;
        a2 += __builtin_bit_cast(float, p2 << 16) * w0 + __builtin_bit_cast(float, p2 & 0xffff0000u) * w1;
        a3 += __builtin_bit_cast(float, p3 << 16) * w0 + __builtin_bit_cast(float, p3 & 0xffff0000u) * w1;
    }
    const float bias = b2[0];
    out[(b0 + 0) * DOUT + o] = a0 + bias;
    out[(b0 + 1) * DOUT + o] = a1 + bias;
    out[(b0 + 2) * DOUT + o] = a2 + bias;
    out[(b0 + 3) * DOUT + o] = a3 + bias;
}

extern "C" void kernel_launch(void* const* d_in, const int* in_sizes, int n_in,
                              void* d_out, int out_size, void* d_ws, size_t ws_size,
                              hipStream_t stream) {
    (void)in_sizes; (void)n_in; (void)out_size; (void)ws_size;
    const float* xs  = (const float*)d_in[0];   // [128,256,256]
    const float* W1x = (const float*)d_in[1];   // [256,1024]
    const float* W1h = (const float*)d_in[2];   // [1024,1024]
    const float* b1  = (const float*)d_in[3];   // [1024]
    const float* W2  = (const float*)d_in[4];   // [1024,256]
    const float* b2  = (const float*)d_in[5];   // scalar
    float* out = (float*)d_out;                 // [256,256]

    // ws: H parity double buffer (1 MB), fragment layout. No flags, no memset:
    // 0xAA poison -> code 0, never matches any expected code (1..15) -> retry.
    short* Hbuf = (short*)d_ws;

    rnn_steps_kernel<<<dim3(NGM, NGN), 128, 0, stream>>>(xs, W1x, W1h, b1, Hbuf);
    // t=128 -> parity 0 holds h_128
    readout_kernel<<<dim3(BB / 4), 256, 0, stream>>>(Hbuf, W2, b2, out);
}